// Round 7
// baseline (335.328 us; speedup 1.0000x reference)
//
#include <hip/hip_runtime.h>
#include <stdint.h>

// LocallyConnected2D: out[b,f,or,oc] = relu( sum_{c,kh,kw} x[b,c,2or+kh,2oc+kw]*W[f,c,2or+kh,2oc+kw] + bias )
// bias raw-reshape: bias_flat[f*OR*OC + or*OC + oc]
//
// B=32 C=32 H=128 W=128 F=64 OR=OC=64.
//
// R11 = R10 resubmitted verbatim (R10 bench died with "container failed twice" — infra
// error, not a kernel verdict; kernel has no hang modes: no barriers, no coop launch,
// no host sync).
//
// R10: NO LDS, NO BARRIERS — pure streaming with cache reuse.
// History: R7 (counted vmcnt, 98us) and R9 (bank conflicts 4.2M->0, still 98us) were both
// individually CORRECT (counters confirmed) yet delivered ~nothing: the residual bottleneck
// is the barrier-phase convoy itself (all pipes <=23% busy because 8-wave blocks alternate
// LDS-storm / VALU-storm phases instead of overlapping; only 2 barrier domains/CU).
// By elimination:
//  - X tile/chunk is 8 KB read by all 16 waves on the CU -> exactly what L1 (32 KB) serves
//    for free. W granules are read by ONE wave (8 bg-lane dup -> coalescer merges to one
//    128-B line). Nothing needs LDS.
//  - Remove staging, barriers, vmcnt discipline. Waves free-run; 4 waves/SIMD TLP hides
//    L1/L2 latency (m114: co-resident waves overlap VALU+VMEM to max, not sum).
//  - No load pinning, no fences (R5 sink / R6+R8 scratch lessons): unconstrained compiler.
// Worst-case (L1 thrash from wave drift): X re-reads 16 x 64 MB = 1 GB from L2, per-XCD
// footprint ~512 KB << 4 MB, at 4.3 TB/s/XCD ~= 30 us, overlapped with W (128 MB, once).
// Verify: LDS=0; dur 50-70us; WRITE ~37MB (ballooning = spill -> revert); FETCH <=200MB
// (>>400MB = cache-reuse falsified).

#define CC  32
#define HH  128
#define WWD 128
#define FF  64
#define ORR 64
#define OCC 64
#define HW  (HH * WWD)         // 16384 floats: per-channel advance
#define CHW (CC * HH * WWD)    // 524288 floats: per-b (x) / per-f (wgt) plane

__global__ __launch_bounds__(512, 4) void lc2d_kernel(
    const float* __restrict__ x, const float* __restrict__ wgt,
    const float* __restrict__ bias, float* __restrict__ out)
{
    const int tid  = threadIdx.x;
    const int id   = blockIdx.x;           // [0,512)
    const int fblk = id >> 8;              // which 32-f half
    const int low  = id & 255;
    // ids differing by 128 share 128-B output lines and the same XCD (128%8==0);
    // pair (id, id+256) reads the same x slice on the same XCD (256%8==0).
    const int oct = ((low & 1) << 1) | (low >> 7);   // 0..3 -> oc0 = oct*16
    const int orr = (low >> 1) & 63;
    const int w0  = oct * 32;                         // 32 w-floats, 128-B aligned
    const int h0  = orr * 2;

    // ---- compute mapping: ocg = w 4-float chunk (2 oc), bg -> 4 b, wv -> 4 f
    const int ocg = tid & 7;
    const int bg  = (tid >> 3) & 7;
    const int wv  = tid >> 6;              // wave 0..7

    // xa[i] source: b = bg*4+i, w-span [w0+ocg*4, +4). Per instr: 8 bg-groups x 128 B
    // contiguous = 8 lines, fully coalesced. Same 8 KB/chunk tile for all 16 waves -> L1.
    const float* gx = x + (((size_t)(bg * 4) * CC) * HH + h0) * WWD + w0 + ocg * 4;
    // wb[q] source: f = fblk*32 + wv*4 + q. 8 ocg-lanes x 16 B = one 128-B line,
    // duplicated across bg (coalescer merges). Each W line fetched once per kernel.
    const float* gw = wgt + (((size_t)(fblk * 32 + wv * 4) * CC) * HH + h0) * WWD + w0 + ocg * 4;

    float acc0[4][4], acc1[4][4];          // [i=b][q=f], oc even / oc odd
#pragma unroll
    for (int i = 0; i < 4; ++i)
#pragma unroll
        for (int q = 0; q < 4; ++q) { acc0[i][q] = 0.f; acc1[i][q] = 0.f; }

#pragma unroll 2
    for (int c = 0; c < CC; ++c) {
#pragma unroll
        for (int s = 0; s < 2; ++s) {      // kh
            float4 xa[4], wb[4];
#pragma unroll
            for (int i = 0; i < 4; ++i)
                xa[i] = *(const float4*)(gx + (size_t)i * CHW + s * WWD);
#pragma unroll
            for (int q = 0; q < 4; ++q)
                wb[q] = *(const float4*)(gw + (size_t)q * CHW + s * WWD);
#pragma unroll
            for (int i = 0; i < 4; ++i)
#pragma unroll
                for (int q = 0; q < 4; ++q) {
                    acc0[i][q] = fmaf(xa[i].x, wb[q].x, acc0[i][q]);
                    acc0[i][q] = fmaf(xa[i].y, wb[q].y, acc0[i][q]);
                    acc1[i][q] = fmaf(xa[i].z, wb[q].z, acc1[i][q]);
                    acc1[i][q] = fmaf(xa[i].w, wb[q].w, acc1[i][q]);
                }
        }
        gx += HW; gw += HW;                // next channel
    }

    // ---- epilogue: bias (raw reshape [F][OR][OC]) + relu, float2 per (b,f)
    const int oc0 = oct * 16 + ocg * 2;
#pragma unroll
    for (int q = 0; q < 4; ++q) {
        const int f = fblk * 32 + wv * 4 + q;
        const float2 bv = *(const float2*)(bias + f * (ORR * OCC) + orr * OCC + oc0);
#pragma unroll
        for (int i = 0; i < 4; ++i) {
            const int b = bg * 4 + i;
            float2 o;
            o.x = fmaxf(acc0[i][q] + bv.x, 0.f);
            o.y = fmaxf(acc1[i][q] + bv.y, 0.f);
            *(float2*)(out + (((b * FF + f) * ORR + orr) * OCC) + oc0) = o;
        }
    }
}

extern "C" void kernel_launch(void* const* d_in, const int* in_sizes, int n_in,
                              void* d_out, int out_size, void* d_ws, size_t ws_size,
                              hipStream_t stream) {
    (void)in_sizes; (void)n_in; (void)d_ws; (void)ws_size; (void)out_size;
    const float* x    = (const float*)d_in[0];
    const float* wgt  = (const float*)d_in[1];
    const float* bias = (const float*)d_in[2];
    float* out        = (float*)d_out;
    lc2d_kernel<<<dim3(512, 1, 1), dim3(512, 1, 1), 0, stream>>>(x, wgt, bias, out);
}

// Round 8
// 272.501 us; speedup vs baseline: 1.2306x; 1.2306x over previous
//
#include <hip/hip_runtime.h>
#include <stdint.h>

// LocallyConnected2D: out[b,f,or,oc] = relu( sum_{c,kh,kw} x[b,c,2or+kh,2oc+kw]*W[f,c,2or+kh,2oc+kw] + bias )
// bias raw-reshape: bias_flat[f*OR*OC + or*OC + oc]
//
// B=32 C=32 H=128 W=128 F=64 OR=OC=64.
//
// R12: more barrier domains + half the barriers. Keeps R9's verified compute core
// (conflict-free swizzled X, broadcast W, counted vmcnt, raw barriers).
//  - R11 post-mortem: no-LDS streaming = 170us. LDS's job is TRAFFIC MULTICAST (16 KB vs
//    256 KB per CU-chunk); without it waves drift, L1 thrashes, L2 path saturates. X
//    staging through LDS is mandatory. R9 core restored.
//  - R9 residual model: LDS floor 3072 cy/chunk, VALU 1024 cy/SIMD, measured 7350 ->
//    >50% rendezvous dead time (2 barriers x 2 domains x 8-wave convoys).
//  - Fix 1: 256-thread blocks (4 waves), f in QUARTERS (16 f/block), grid 1024.
//    LDS 3-deep x (8KB X + 4KB W) = 36 KB -> 4 blocks/CU = 4 independent barrier
//    domains, 16 waves/CU. Stalled domain overlaps 3 computing domains.
//  - Fix 2: ONE barrier per chunk: with a 3-deep ring, top-of-chunk barrier proves all
//    waves finished chunk it-1 -> buf (it-1)%3 free -> issue chunk it+2 into it after
//    the barrier. 32 rendezvous (was 64).
//  - vmcnt: 3 gloads/wave/chunk (2 X + 1 W); steady wait vmcnt(3), 0 only at it=31.
//  - ids (low + fq*256) share the X tile on the same XCD (256%8==0).
// Verify: WG 256, LDS 36864, conflicts 0, absmax bit-identical; dur ~60-75us.

#define CC  32
#define HH  128
#define WWD 128
#define FF  64
#define ORR 64
#define OCC 64
#define NIT 32                 // chunks = channels
#define HW  (HH * WWD)         // per-channel advance in floats
#define CHW (CC * HH * WWD)

__global__ __launch_bounds__(256, 4) void lc2d_kernel(
    const float* __restrict__ x, const float* __restrict__ wgt,
    const float* __restrict__ bias, float* __restrict__ out)
{
    // per chunk: X tile 2kh x 32b x 32w = 2048 fl (8 KB); W quarter 2kh x 16f x 32w = 1024 fl (4 KB)
    __shared__ __align__(16) float Xs[3][2048];   // 24 KB
    __shared__ __align__(16) float Ws[3][1024];   // 12 KB  (36 KB total -> 4 blocks/CU)

    const int tid = threadIdx.x;
    const int id  = blockIdx.x;            // [0,1024)
    const int fq  = id >> 8;               // f quarter: f in [fq*16, fq*16+16)
    const int low = id & 255;
    const int oct = ((low & 1) << 1) | (low >> 7);   // 0..3 -> oc0 = oct*16
    const int orr = (low >> 1) & 63;
    const int w0  = oct * 32;                         // 32 w-floats, 128-B aligned
    const int h0  = orr * 2;

    const int lane = tid & 63;
    const int wv   = tid >> 6;        // wave 0..3
    const int chk  = lane & 7;        // 16-B chunk within a 128-B row
    const int sub  = lane >> 3;       // row within an 8-row slot

    // ---- X staging (2 slots/wave): slot k = wv*2+j covers slice s = k>>2, quarter qh = k&3.
    // Swizzled source b = sub*4 + qh (R9 layout: granule (b,chk) of slice s lands at
    // per-slice position (b&3)*64 + (b>>2)*8 + chk -> lane-linear conflict-free reads).
    const float* gxA;  // j=0: k = wv*2
    const float* gxB;  // j=1: k = wv*2+1
    {
        const int kA = wv * 2, kB = wv * 2 + 1;
        const int bA = sub * 4 + (kA & 3), sA = kA >> 2;
        const int bB = sub * 4 + (kB & 3), sB = kB >> 2;
        gxA = x + (((bA * CC) * HH) + h0 + sA) * WWD + w0 + chk * 4;
        gxB = x + (((bB * CC) * HH) + h0 + sB) * WWD + w0 + chk * 4;
    }
    // ---- W staging (1 slot/wave): rows r = wv*8+sub in [0,32): s = r>>4, fl = r&15.
    const float* gw;
    {
        const int r = wv * 8 + sub;
        gw = wgt + ((((fq * 16 + (r & 15)) * CC) * HH) + h0 + (r >> 4)) * WWD + w0 + chk * 4;
    }

    auto issue = [&](int p) {
        __builtin_amdgcn_global_load_lds(
            (const __attribute__((address_space(1))) void*)gxA,
            (__attribute__((address_space(3))) void*)(&Xs[p][(wv * 2) * 256 + 0]), 16, 0, 0);
        __builtin_amdgcn_global_load_lds(
            (const __attribute__((address_space(1))) void*)gxB,
            (__attribute__((address_space(3))) void*)(&Xs[p][(wv * 2 + 1) * 256]), 16, 0, 0);
        __builtin_amdgcn_global_load_lds(
            (const __attribute__((address_space(1))) void*)gw,
            (__attribute__((address_space(3))) void*)(&Ws[p][wv * 256]), 16, 0, 0);
        gxA += HW; gxB += HW; gw += HW;   // next channel
    };

    // ---- compute mapping: ocg = w 4-float chunk (2 oc), bg -> 4 b, wv -> 4 f
    const int ocg = tid & 7;
    const int bg  = (tid >> 3) & 7;

    float acc0[4][4], acc1[4][4];          // [i=b][q=f], oc even / oc odd
#pragma unroll
    for (int i = 0; i < 4; ++i)
#pragma unroll
        for (int q = 0; q < 4; ++q) { acc0[i][q] = 0.f; acc1[i][q] = 0.f; }

    // prologue: chunks 0,1 in flight (6 loads/wave outstanding)
    issue(0); issue(1);

    int p = 0;                             // buf of chunk it (ring of 3)
    for (int it = 0; it < NIT; ++it) {
        // own chunk-it loads done (chunk it+1's 3 may fly); barrier -> everyone's done.
        if (it < NIT - 1) asm volatile("s_waitcnt vmcnt(3)");
        else              asm volatile("s_waitcnt vmcnt(0)");
        __builtin_amdgcn_sched_barrier(0);
        __builtin_amdgcn_s_barrier();      // also proves buf (it-1)%3 free
        __builtin_amdgcn_sched_barrier(0);
        if (it + 2 < NIT) {
            const int pn = (p + 2) % 3;    // == (it-1)%3, just freed
            issue(pn);
        }
        __builtin_amdgcn_sched_barrier(0);

        const float* Xp = Xs[p];
        const float* Wp = Ws[p];
#pragma unroll
        for (int s = 0; s < 2; ++s) {      // kh
            // X swizzled: granule (b=bg*4+i, chk=ocg) at float off s*1024 + i*256 + lane*4
            const float4* xr = (const float4*)(Xp + s * 1024 + (lane << 2));
            // W row-major quarter: row (s*16 + wv*4 + q), col ocg*4; bg-broadcast (free)
            const float4* wr = (const float4*)(Wp + s * 512 + wv * 128 + ocg * 4);
            float4 xa[4], wb[4];
#pragma unroll
            for (int i = 0; i < 4; ++i) xa[i] = xr[i * 64];  // b = bg*4 + i
#pragma unroll
            for (int q = 0; q < 4; ++q) wb[q] = wr[q * 8];   // f = fq*16 + wv*4 + q
#pragma unroll
            for (int i = 0; i < 4; ++i)
#pragma unroll
                for (int q = 0; q < 4; ++q) {
                    acc0[i][q] = fmaf(xa[i].x, wb[q].x, acc0[i][q]);
                    acc0[i][q] = fmaf(xa[i].y, wb[q].y, acc0[i][q]);
                    acc1[i][q] = fmaf(xa[i].z, wb[q].z, acc1[i][q]);
                    acc1[i][q] = fmaf(xa[i].w, wb[q].w, acc1[i][q]);
                }
        }
        p = (p + 1) % 3;
    }

    // ---- epilogue: bias (raw reshape [F][OR][OC]) + relu, float2 per (b,f)
    const int oc0 = oct * 16 + ocg * 2;
#pragma unroll
    for (int q = 0; q < 4; ++q) {
        const int f = fq * 16 + wv * 4 + q;
        const float2 bv = *(const float2*)(bias + f * (ORR * OCC) + orr * OCC + oc0);
#pragma unroll
        for (int i = 0; i < 4; ++i) {
            const int b = bg * 4 + i;
            float2 o;
            o.x = fmaxf(acc0[i][q] + bv.x, 0.f);
            o.y = fmaxf(acc1[i][q] + bv.y, 0.f);
            *(float2*)(out + (((b * FF + f) * ORR + orr) * OCC) + oc0) = o;
        }
    }
}

extern "C" void kernel_launch(void* const* d_in, const int* in_sizes, int n_in,
                              void* d_out, int out_size, void* d_ws, size_t ws_size,
                              hipStream_t stream) {
    (void)in_sizes; (void)n_in; (void)d_ws; (void)ws_size; (void)out_size;
    const float* x    = (const float*)d_in[0];
    const float* wgt  = (const float*)d_in[1];
    const float* bias = (const float*)d_in[2];
    float* out        = (float*)d_out;
    lc2d_kernel<<<dim3(1024, 1, 1), dim3(256, 1, 1), 0, stream>>>(x, wgt, bias, out);
}